// Round 4
// baseline (369.616 us; speedup 1.0000x reference)
//
#include <hip/hip_runtime.h>

#define LVLS  16
#define TSZ   524288u          // 2^19
#define TMASK (TSZ - 1u)
#define PRIME 2654435761u

// floor(16 * g^l), g = 128^(1/15) — matches np float64 floor then f32 cast
__constant__ float RES[LVLS] = {16.f, 22.f, 30.f, 42.f, 58.f, 80.f, 111.f, 153.f,
                                212.f, 294.f, 406.f, 561.f, 776.f, 1072.f, 1482.f, 2048.f};

typedef __bf16 bf16x8 __attribute__((ext_vector_type(8)));
typedef float  f32x4  __attribute__((ext_vector_type(4)));

union Frag {
    uint4          q;
    unsigned       u[4];
    unsigned short s[8];
    bf16x8         v;
};

static __device__ __forceinline__ unsigned short f2bf(float f) {
    unsigned u = __float_as_uint(f);
    u += 0x7FFFu + ((u >> 16) & 1u);          // RNE; inputs finite, non-NaN
    return (unsigned short)(u >> 16);
}
static __device__ __forceinline__ unsigned pack2(float a, float b) {
    return (unsigned)f2bf(a) | ((unsigned)f2bf(b) << 16);
}
static __device__ __forceinline__ void lds_fence() {
    asm volatile("s_waitcnt lgkmcnt(0)" ::: "memory");
}
static __device__ __forceinline__ unsigned cell_key(float2 v) {
    unsigned cx = (unsigned)(v.x * 256.f); cx = cx > 255u ? 255u : cx;
    unsigned cy = (unsigned)(v.y * 256.f); cy = cy > 255u ? 255u : cy;
    return (cy << 8) | cx;
}

// ============ sort: counting sort by 256x256 spatial cell ============
__global__ __launch_bounds__(256) void k_zero(unsigned* __restrict__ hist) {
    hist[blockIdx.x * 256 + threadIdx.x] = 0u;
}

__global__ __launch_bounds__(256) void k_hist(const float2* __restrict__ x,
                                              unsigned* __restrict__ hist, int N) {
    const int n = blockIdx.x * 256 + threadIdx.x;
    if (n >= N) return;
    atomicAdd(&hist[cell_key(x[n])], 1u);
}

__global__ __launch_bounds__(1024) void k_scan(unsigned* __restrict__ hist) {
    __shared__ unsigned ps[1024];
    const int t = threadIdx.x;
    unsigned s = 0;
    for (int i = 0; i < 64; ++i) s += hist[t * 64 + i];
    ps[t] = s;
    __syncthreads();
    for (int off = 1; off < 1024; off <<= 1) {
        const unsigned v = (t >= off) ? ps[t - off] : 0u;
        __syncthreads();
        ps[t] += v;
        __syncthreads();
    }
    unsigned run = ps[t] - s;                 // exclusive prefix
    for (int i = 0; i < 64; ++i) {
        const unsigned cnt = hist[t * 64 + i];
        hist[t * 64 + i] = run;               // in-place: counts -> offsets
        run += cnt;
    }
}

__global__ __launch_bounds__(256) void k_scatter(const float2* __restrict__ x,
                                                 unsigned* __restrict__ hist,
                                                 int* __restrict__ perm,
                                                 float2* __restrict__ xs, int N) {
    const int n = blockIdx.x * 256 + threadIdx.x;
    if (n >= N) return;
    const float2 v = x[n];
    const unsigned pos = atomicAdd(&hist[cell_key(v)], 1u);
    perm[pos] = n;
    xs[pos] = v;
}

// ============ precompute MLP B-operand fragments (bf16) into ws ============
// Layouts (m89/m120-verified): B[k=quad*8+j][n=lane&15] per 16-col tile.
__global__ __launch_bounds__(64) void k_frag(
    const float* __restrict__ W0, const float* __restrict__ W1,
    const float* __restrict__ W2, uint4* __restrict__ frg)
{
    const int lane = threadIdx.x;
    const int c = lane & 15, quad = lane >> 4;
    Frag t;
    for (int f = 0; f < 4; ++f) {
        #pragma unroll
        for (int j = 0; j < 8; ++j) t.s[j] = f2bf(W0[(quad * 8 + j) * 64 + f * 16 + c]);
        frg[f * 64 + lane] = t.q;
    }
    for (int ff = 0; ff < 8; ++ff) {
        const int kt = ff >> 2, tt = ff & 3;
        #pragma unroll
        for (int j = 0; j < 8; ++j)
            t.s[j] = f2bf(W1[(kt * 32 + quad * 8 + j) * 64 + tt * 16 + c]);
        frg[(4 + ff) * 64 + lane] = t.q;
    }
    for (int f = 0; f < 2; ++f) {
        #pragma unroll
        for (int j = 0; j < 8; ++j) {
            const float v = (c < 3) ? W2[(f * 32 + quad * 8 + j) * 3 + c] : 0.f;
            t.s[j] = f2bf(v);
        }
        frg[(12 + f) * 64 + lane] = t.q;
    }
}

// ============ encode: 1 thread = (point, level); 1 level per block ============
// XCD swizzle: level l's blocks at blockIdx%8 == l%8 -> XCD k serves tables k, k+8.
__global__ __launch_bounds__(256) void ngp_encode(
    const float2* __restrict__ xs, const float* __restrict__ tables,
    unsigned* __restrict__ feat, int N, int PB)
{
    const int g  = blockIdx.x;
    const int r  = g & 7;
    const int i  = g >> 3;
    const int hi = (i >= PB);
    const int l  = r + (hi << 3);
    const int pb = i - (hi ? PB : 0);
    const int n  = pb * 256 + threadIdx.x;
    if (n >= N) return;

    const float2 xy = xs[n];
    const float res = RES[l];
    const float sx = xy.x * res, sy = xy.y * res;
    const float fx = floorf(sx),  fy = floorf(sy);
    const float ux = sx - fx,     uy = sy - fy;
    const unsigned ix = (unsigned)(int)fx, iy = (unsigned)(int)fy;
    const unsigned hy0 = iy * PRIME, hy1 = (iy + 1u) * PRIME;
    const unsigned i00 = (ix ^ hy0) & TMASK;
    const unsigned i10 = ((ix + 1u) ^ hy0) & TMASK;
    const unsigned i01 = (ix ^ hy1) & TMASK;
    const unsigned i11 = ((ix + 1u) ^ hy1) & TMASK;
    const float2* tb = (const float2*)(tables + (size_t)l * (TSZ * 2));
    const float2 f00 = tb[i00], f10 = tb[i10], f01 = tb[i01], f11 = tb[i11];
    const float w00 = (1.f - ux) * (1.f - uy);
    const float w10 = ux * (1.f - uy);
    const float w01 = (1.f - ux) * uy;
    const float w11 = ux * uy;
    const float e0 = w00*f00.x + w10*f10.x + w01*f01.x + w11*f11.x;
    const float e1 = w00*f00.y + w10*f10.y + w01*f01.y + w11*f11.y;
    feat[(size_t)l * N + n] = pack2(e0, e1);
}

// ============ MLP via MFMA 16x16x32 bf16; 8 tiles/wave, interleaved pairs ============
__global__ __launch_bounds__(256) void ngp_mlp(
    const unsigned* __restrict__ feat, const uint4* __restrict__ frg,
    const float* __restrict__ b0, const float* __restrict__ b1,
    const float* __restrict__ b2,
    const int* __restrict__ perm, float* __restrict__ out, int N)
{
    __shared__ __align__(16) unsigned short hscr[4][2][16][72];

    const int tid  = threadIdx.x;
    const int lane = tid & 63;
    const int w    = tid >> 6;
    const int c    = lane & 15;
    const int quad = lane >> 4;

    Frag B0f[4], B1f[8], B2f[2];
    #pragma unroll
    for (int t = 0; t < 4; ++t) B0f[t].q = frg[t * 64 + lane];
    #pragma unroll
    for (int f = 0; f < 8; ++f) B1f[f].q = frg[(4 + f) * 64 + lane];
    #pragma unroll
    for (int f = 0; f < 2; ++f) B2f[f].q = frg[(12 + f) * 64 + lane];

    float bias0[4], bias1[4];
    #pragma unroll
    for (int t = 0; t < 4; ++t) { bias0[t] = b0[t * 16 + c]; bias1[t] = b1[t * 16 + c]; }
    const float bias2 = (c < 3) ? b2[c] : 0.f;

    const int base = blockIdx.x * 512 + w * 128;

    // prefetch all 8 tiles' A0 fragments (independent, coalesced)
    Frag a0[8];
    #pragma unroll
    for (int tt = 0; tt < 8; ++tt)
        #pragma unroll
        for (int i = 0; i < 4; ++i)
            a0[tt].u[i] = feat[(size_t)(quad * 4 + i) * N + base + tt * 16 + c];

    #pragma unroll
    for (int gpair = 0; gpair < 4; ++gpair) {
        const int t0n = base + (2 * gpair) * 16;
        const int t1n = base + (2 * gpair + 1) * 16;
        if (t0n + 16 > N) break;

        int p[2][4];
        #pragma unroll
        for (int s = 0; s < 2; ++s)
            #pragma unroll
            for (int rr = 0; rr < 4; ++rr) {
                const int idx = (s ? t1n : t0n) + quad * 4 + rr;
                p[s][rr] = perm ? perm[idx] : idx;
            }

        f32x4 acc[2][4];
        #pragma unroll
        for (int s = 0; s < 2; ++s)
            #pragma unroll
            for (int t = 0; t < 4; ++t) {
                f32x4 cin = {bias0[t], bias0[t], bias0[t], bias0[t]};
                acc[s][t] = __builtin_amdgcn_mfma_f32_16x16x32_bf16(
                    a0[2 * gpair + s].v, B0f[t].v, cin, 0, 0, 0);
            }

        lds_fence();
        #pragma unroll
        for (int s = 0; s < 2; ++s)
            #pragma unroll
            for (int t = 0; t < 4; ++t)
                #pragma unroll
                for (int rr = 0; rr < 4; ++rr)
                    hscr[w][s][quad * 4 + rr][t * 16 + c] = f2bf(fmaxf(acc[s][t][rr], 0.f));
        lds_fence();

        Frag a1[2][2];
        #pragma unroll
        for (int s = 0; s < 2; ++s)
            #pragma unroll
            for (int kt = 0; kt < 2; ++kt)
                a1[s][kt].q = *(const uint4*)&hscr[w][s][c][kt * 32 + quad * 8];

        #pragma unroll
        for (int s = 0; s < 2; ++s)
            #pragma unroll
            for (int t = 0; t < 4; ++t) {
                f32x4 cin = {bias1[t], bias1[t], bias1[t], bias1[t]};
                cin = __builtin_amdgcn_mfma_f32_16x16x32_bf16(a1[s][0].v, B1f[t].v, cin, 0, 0, 0);
                acc[s][t] = __builtin_amdgcn_mfma_f32_16x16x32_bf16(a1[s][1].v, B1f[4 + t].v, cin, 0, 0, 0);
            }

        lds_fence();
        #pragma unroll
        for (int s = 0; s < 2; ++s)
            #pragma unroll
            for (int t = 0; t < 4; ++t)
                #pragma unroll
                for (int rr = 0; rr < 4; ++rr)
                    hscr[w][s][quad * 4 + rr][t * 16 + c] = f2bf(fmaxf(acc[s][t][rr], 0.f));
        lds_fence();

        Frag a2[2][2];
        #pragma unroll
        for (int s = 0; s < 2; ++s)
            #pragma unroll
            for (int kt = 0; kt < 2; ++kt)
                a2[s][kt].q = *(const uint4*)&hscr[w][s][c][kt * 32 + quad * 8];

        #pragma unroll
        for (int s = 0; s < 2; ++s) {
            f32x4 cin2 = {bias2, bias2, bias2, bias2};
            cin2 = __builtin_amdgcn_mfma_f32_16x16x32_bf16(a2[s][0].v, B2f[0].v, cin2, 0, 0, 0);
            const f32x4 o = __builtin_amdgcn_mfma_f32_16x16x32_bf16(a2[s][1].v, B2f[1].v, cin2, 0, 0, 0);
            if (c < 3) {
                #pragma unroll
                for (int rr = 0; rr < 4; ++rr) {
                    const float sg = 1.f / (1.f + __expf(-o[rr]));
                    out[(size_t)p[s][rr] * 3 + c] = sg;
                }
            }
        }
    }
}

extern "C" void kernel_launch(void* const* d_in, const int* in_sizes, int n_in,
                              void* d_out, int out_size, void* d_ws, size_t ws_size,
                              hipStream_t stream) {
    const float* x      = (const float*)d_in[0];
    const float* tables = (const float*)d_in[1];
    const float* W0     = (const float*)d_in[2];
    const float* b0     = (const float*)d_in[3];
    const float* W1     = (const float*)d_in[4];
    const float* b1     = (const float*)d_in[5];
    const float* W2     = (const float*)d_in[6];
    const float* b2     = (const float*)d_in[7];
    float* out = (float*)d_out;

    const int N  = in_sizes[0] / 2;
    const int PB = (N + 255) / 256;
    char* ws = (char*)d_ws;

    // ws layout
    const size_t off_frag = 0;                         // 14*64*16 = 14336 B
    const size_t off_feat = 16384;                     // LVLS*N*4 = 64 MB
    const size_t feat_sz  = (size_t)LVLS * N * 4;
    const size_t off_xs   = off_feat + feat_sz;        // 8 MB
    const size_t off_perm = off_xs + (size_t)N * 8;    // 4 MB
    const size_t off_hist = off_perm + (size_t)N * 4;  // 256 KB
    const size_t need     = off_hist + 65536 * 4;
    const bool use_sort = (ws_size >= need);

    uint4*    frg  = (uint4*)(ws + off_frag);
    unsigned* feat = (unsigned*)(ws + off_feat);
    float2*   xs   = (float2*)(ws + off_xs);
    int*      perm = (int*)(ws + off_perm);
    unsigned* hist = (unsigned*)(ws + off_hist);

    k_frag<<<1, 64, 0, stream>>>(W0, W1, W2, frg);

    const float2* enc_x = (const float2*)x;
    const int* mlp_perm = nullptr;
    if (use_sort) {
        k_zero<<<256, 256, 0, stream>>>(hist);
        k_hist<<<(N + 255) / 256, 256, 0, stream>>>((const float2*)x, hist, N);
        k_scan<<<1, 1024, 0, stream>>>(hist);
        k_scatter<<<(N + 255) / 256, 256, 0, stream>>>((const float2*)x, hist, perm, xs, N);
        enc_x = xs;
        mlp_perm = perm;
    }

    ngp_encode<<<16 * PB, 256, 0, stream>>>(enc_x, tables, feat, N, PB);
    ngp_mlp<<<(N + 511) / 512, 256, 0, stream>>>(feat, frg, b0, b1, b2, mlp_perm, out, N);
}